// Round 5
// baseline (168.979 us; speedup 1.0000x reference)
//
#include <hip/hip_runtime.h>

#define BATCH 512
#define SEQ   512
#define VOCAB 1000
#define EMB   100
#define UNITS 64

// 2*log2(e): fold tanh's exp(2y)=exp2(K*y) scale into P and Whh at load time.
#define KSCALE 2.885390081777926814f

typedef float v2f __attribute__((ext_vector_type(2)));
typedef float v4f __attribute__((ext_vector_type(4)));

// ---------------------------------------------------------------------------
// Kernel 1: P[v][u] = (sum_d emb[v][d] * Wxh[d][u] + b[u]) * KSCALE
// ---------------------------------------------------------------------------
__global__ __launch_bounds__(256) void proj_kernel(
    const float* __restrict__ emb, const float* __restrict__ Wxh,
    const float* __restrict__ bias, float* __restrict__ P) {
  const int v = blockIdx.x * 4 + (threadIdx.x >> 6);
  const int u = threadIdx.x & 63;
  const float* e = emb + v * EMB;
  float a0 = 0.f, a1 = 0.f, a2 = 0.f, a3 = 0.f;
#pragma unroll
  for (int d = 0; d < EMB; d += 4) {
    a0 = fmaf(e[d + 0], Wxh[(d + 0) * UNITS + u], a0);
    a1 = fmaf(e[d + 1], Wxh[(d + 1) * UNITS + u], a1);
    a2 = fmaf(e[d + 2], Wxh[(d + 2) * UNITS + u], a2);
    a3 = fmaf(e[d + 3], Wxh[(d + 3) * UNITS + u], a3);
  }
  P[v * UNITS + u] = (((a0 + a1) + (a2 + a3)) + bias[u]) * KSCALE;
}

// ---------------------------------------------------------------------------
// Kernel 2: sequential scan, ONE wave per batch row.
//   h[j] <- tanh(P[tok_t][j] + sum_i h[i]*Whh[i][j])
//
// r1-r4 post-mortem across 4 structurally different implementations (LDS
// split-2/split-4, full register butterfly, DPP gather): step time =
// instr_count x ~5.2-7.4 cyc in ALL cases; VALUBusy == VALU_count*2/step
// exactly; removing LDS entirely (r4) changed nothing. Model: a SOLO wave
// issues ~1 instruction per ~5-6 cycles regardless of ILP (sequencer
// cadence). Therefore: minimize total instructions per step, nothing else.
//
// This version: no-split LDS broadcast (lane l computes y[l] directly; every
// lane reads all 64 h via 16 broadcast ds_read_b128 -- no merge stages, no
// permlane hazards), with every removable instruction removed:
//   - KSCALE pre-folded into P and Whh: tanh = exp2, add, rcp, fma (4 instr)
//   - a_cur folded into the final horizontal add
//   - accumulators initialized by pk_mul (no zero-init movs)
//   - no token cndmask: tail prefetch re-issued per 64-chunk (1 extra load
//     per 64 steps)
//   - pair extraction via shufflevector (register aliasing, no v_movs)
// Budget: 16 ds_read + 1 ds_write + 32 pk_fma-class + 5 combine + 4 tanh +
// 4 prefetch + ~1.5 loop ~= 64 instrs/step.
// ---------------------------------------------------------------------------
__global__ __launch_bounds__(64)
__attribute__((amdgpu_waves_per_eu(1, 1)))
void scan_kernel(
    const int* __restrict__ tok, const float* __restrict__ P,
    const float* __restrict__ Whh, const float* __restrict__ Wout,
    const float* __restrict__ bout, float* __restrict__ out) {
  const int row  = blockIdx.x;
  const int lane = threadIdx.x;

  __shared__ __align__(16) v4f hs4[UNITS / 4];  // 64 floats, broadcast buffer
  float* hsf = (float*)hs4;

  // Whh column `lane`, KSCALE-pre-scaled, as 32 packed i-pairs in VGPRs.
  v2f wv[UNITS / 2];
#pragma unroll
  for (int k = 0; k < UNITS / 2; ++k) {
    float wx = Whh[(2 * k + 0) * UNITS + lane] * KSCALE;
    float wy = Whh[(2 * k + 1) * UNITS + lane] * KSCALE;
    asm volatile("" : "+v"(wx), "+v"(wy));
    wv[k].x = wx;
    wv[k].y = wy;
  }

  // All 512 tokens of this row, pre-scaled by UNITS (coalesced loads).
  int tokv[SEQ / 64];
  const int* trow = tok + (long)row * SEQ;
#pragma unroll
  for (int c = 0; c < SEQ / 64; ++c) {
    int t = trow[c * 64 + lane] * UNITS;
    asm volatile("" : "+v"(t));
    tokv[c] = t;
  }

  // h_0 = 0 (single wave: same-wave LDS ops are in-order, no barriers).
  hsf[lane] = 0.f;

  // Prefetch P row for t=0.
  int tk0 = __builtin_amdgcn_readlane(tokv[0], 0);
  float a = P[(long)tk0 + lane];

#pragma unroll
  for (int c = 0; c < SEQ / 64; ++c) {
#pragma unroll 2
    for (int tt = 0; tt < 64; ++tt) {
      float a_cur = a;
      // Prefetch next step's P row. At tt==63 this re-reads index (c,0)
      // (valid address, discarded); the chunk boundary re-issues below.
      int tkn = __builtin_amdgcn_readlane(tokv[c], (tt + 1) & 63);
      a = P[(long)tkn + lane];

      // ---- 16 broadcast ds_read_b128, issued back-to-back. ----
      v4f hq[UNITS / 4];
#pragma unroll
      for (int q = 0; q < UNITS / 4; ++q) hq[q] = hs4[q];

      // ---- 64 MACs: 4 mul-init + 28 pk_fma, 4 chains of depth 8. ----
      v2f acc0, acc1, acc2, acc3;
#pragma unroll
      for (int q = 0; q < UNITS / 4; ++q) {
        v2f lo = __builtin_shufflevector(hq[q], hq[q], 0, 1);
        v2f hi = __builtin_shufflevector(hq[q], hq[q], 2, 3);
        if (q == 0) {
          acc0 = lo * wv[0];
          acc1 = hi * wv[1];
        } else if (q == 1) {
          acc2 = lo * wv[2];
          acc3 = hi * wv[3];
        } else if (q & 1) {
          acc2 += lo * wv[2 * q + 0];
          acc3 += hi * wv[2 * q + 1];
        } else {
          acc0 += lo * wv[2 * q + 0];
          acc1 += hi * wv[2 * q + 1];
        }
      }
      v2f rr = (acc0 + acc1) + (acc2 + acc3);
      float y = (rr.x + rr.y) + a_cur;  // y pre-scaled by K = 2*log2(e)

      // tanh: 1 - 2*rcp(exp2(y)+1)  (saturation-safe at both extremes)
      float ex = __builtin_amdgcn_exp2f(y);
      float h = fmaf(-2.f, __builtin_amdgcn_rcpf(ex + 1.f), 1.f);

      // Publish h for the next step (in-order DS pipe, no barrier needed).
      hsf[lane] = h;
    }
    if (c + 1 < SEQ / 64) {
      int tkb = __builtin_amdgcn_readlane(tokv[c + 1], 0);
      a = P[(long)tkb + lane];
    }
  }

  // out[row] = sigmoid(sum_j h[j]*Wout[j] + bout)
  float psum = hsf[lane] * Wout[lane];
#pragma unroll
  for (int off = 32; off > 0; off >>= 1) psum += __shfl_xor(psum, off);
  if (lane == 0) out[row] = 1.f / (1.f + __expf(-(psum + bout[0])));
}

extern "C" void kernel_launch(void* const* d_in, const int* in_sizes, int n_in,
                              void* d_out, int out_size, void* d_ws, size_t ws_size,
                              hipStream_t stream) {
  const int*   tok  = (const int*)  d_in[0];  // [BATCH, SEQ] int32
  const float* emb  = (const float*)d_in[1];  // [VOCAB, EMB]
  const float* Wxh  = (const float*)d_in[2];  // [EMB, UNITS]
  const float* Whh  = (const float*)d_in[3];  // [UNITS, UNITS]
  const float* bias = (const float*)d_in[4];  // [UNITS]
  const float* Wout = (const float*)d_in[5];  // [UNITS, 1]
  const float* bout = (const float*)d_in[6];  // [1]
  float* out = (float*)d_out;                 // [BATCH, 1] fp32

  float* P = (float*)d_ws;                    // VOCAB*UNITS fp32 = 256 KB

  proj_kernel<<<VOCAB / 4, 256, 0, stream>>>(emb, Wxh, bias, P);
  scan_kernel<<<BATCH, 64, 0, stream>>>(tok, P, Whh, Wout, bout, out);
}

// Round 6
// 162.845 us; speedup vs baseline: 1.0377x; 1.0377x over previous
//
#include <hip/hip_runtime.h>

#define BATCH 512
#define SEQ   512
#define VOCAB 1000
#define EMB   100
#define UNITS 64

// 2*log2(e): exp(2y) = exp2(KSCALE*y); folded into P and Whh at load time.
#define KSCALE 2.885390081777926814f

typedef float v2f __attribute__((ext_vector_type(2)));
typedef float v4f __attribute__((ext_vector_type(4)));
typedef int   v2i __attribute__((ext_vector_type(2)));

// ---------------------------------------------------------------------------
// Kernel 1: P[v][u] = KSCALE * ( sum_d emb[v][d]*Wxh[d][u] + b[u] + colsum_u )
// where colsum_u = sum_i Whh[i][u].  The colsum term comes from the scan's
// r-substitution: h = 1 - 2r  =>  sum_i h_i W_iu = colsum_u - 2 sum_i r_i W_iu.
// ---------------------------------------------------------------------------
__global__ __launch_bounds__(256) void proj_kernel(
    const float* __restrict__ emb, const float* __restrict__ Wxh,
    const float* __restrict__ bias, const float* __restrict__ Whh,
    float* __restrict__ P) {
  const int v = blockIdx.x * 4 + (threadIdx.x >> 6);
  const int u = threadIdx.x & 63;
  const float* e = emb + v * EMB;
  float a0 = 0.f, a1 = 0.f, a2 = 0.f, a3 = 0.f;
#pragma unroll
  for (int d = 0; d < EMB; d += 4) {
    a0 = fmaf(e[d + 0], Wxh[(d + 0) * UNITS + u], a0);
    a1 = fmaf(e[d + 1], Wxh[(d + 1) * UNITS + u], a1);
    a2 = fmaf(e[d + 2], Wxh[(d + 2) * UNITS + u], a2);
    a3 = fmaf(e[d + 3], Wxh[(d + 3) * UNITS + u], a3);
  }
  float cs = 0.f;
#pragma unroll
  for (int i = 0; i < UNITS; ++i) cs += Whh[i * UNITS + u];
  P[v * UNITS + u] = (((a0 + a1) + (a2 + a3)) + bias[u] + cs) * KSCALE;
}

// ---------------------------------------------------------------------------
// Kernel 2: sequential scan, ONE wave per batch row. r1 structure (split-2,
// the measured sweet spot: 492 cyc/step) with the serial tail shortened:
//
// r5 post-mortem fit across r1-r5: step ~= 4*N_valu + 8*N_ds + ~260 fixed.
// r1 -- the fastest -- still paid mul+mul+exp2 (__expf(2s)) and a TRUE IEEE
// DIVIDE (~10 serial instrs) in its tanh. Fix: publish r = rcp(exp2(Ky)+1)
// instead of h (h = 1-2r). Then
//   y_j = (x_j + b_j + colsum_j) - 2 sum_i r_i W_ij
// with colsum folded into P (proj) and -2K folded into the weight registers.
// Chain tail is now: swap-merge -> add a -> exp2 -> add 1 -> rcp -> ds_write.
// Initial state h=0  <=>  r=0.5.
// ---------------------------------------------------------------------------
__global__ __launch_bounds__(64)
__attribute__((amdgpu_waves_per_eu(1, 1)))
void scan_kernel(
    const int* __restrict__ tok, const float* __restrict__ P,
    const float* __restrict__ Whh, const float* __restrict__ Wout,
    const float* __restrict__ bout, float* __restrict__ out) {
  const int row  = blockIdx.x;
  const int lane = threadIdx.x;
  const int g    = lane >> 5;   // which half of the i-dimension this lane sums
  const int m    = lane & 31;

  __shared__ __align__(16) v4f hs4[UNITS / 4];  // 64 floats (r-state)
  float* hsf = (float*)hs4;

  // Weights scaled by -2*KSCALE (the r-substitution + exp2 fold):
  //   wv0[k2] = -2K * {Whh[32g+2k2][m],    Whh[32g+2k2+1][m]}
  //   wv1[k2] = -2K * {Whh[32g+2k2][m+32], Whh[32g+2k2+1][m+32]}
  v2f wv0[UNITS / 4], wv1[UNITS / 4];
#pragma unroll
  for (int k2 = 0; k2 < UNITS / 4; ++k2) {
    const int i0 = 32 * g + 2 * k2;
    float ax = Whh[(i0 + 0) * UNITS + m] * (-2.f * KSCALE);
    float ay = Whh[(i0 + 1) * UNITS + m] * (-2.f * KSCALE);
    float bx = Whh[(i0 + 0) * UNITS + m + 32] * (-2.f * KSCALE);
    float by = Whh[(i0 + 1) * UNITS + m + 32] * (-2.f * KSCALE);
    asm volatile("" : "+v"(ax), "+v"(ay), "+v"(bx), "+v"(by));
    wv0[k2].x = ax; wv0[k2].y = ay;
    wv1[k2].x = bx; wv1[k2].y = by;
  }

  // All 512 tokens of this row, pre-scaled by UNITS (coalesced loads).
  int tokv[SEQ / 64];
  const int* trow = tok + (long)row * SEQ;
#pragma unroll
  for (int c = 0; c < SEQ / 64; ++c) {
    int t = trow[c * 64 + lane] * UNITS;
    asm volatile("" : "+v"(t));
    tokv[c] = t;
  }

  // h_0 = 0  <=>  r_0 = 0.5 (single wave: in-order DS pipe, no barriers).
  hsf[lane] = 0.5f;
  float r_last = 0.5f;

  // Prefetch P row for t=0.
  int tk0 = __builtin_amdgcn_readlane(tokv[0], 0);
  float a = P[(long)tk0 + lane];

#pragma unroll
  for (int c = 0; c < SEQ / 64; ++c) {
#pragma unroll 2
    for (int tt = 0; tt < 64; ++tt) {
      float a_cur = a;
      // Prefetch next timestep's P row (consumed one full step later).
      int ntt = (tt + 1) & 63;
      int tkn = __builtin_amdgcn_readlane(tokv[c], ntt);
      a = P[(long)tkn + lane];

      // ---- Read only MY half of r: 8x ds_read_b128, back-to-back. ----
      v4f hq[UNITS / 8];
#pragma unroll
      for (int q = 0; q < UNITS / 8; ++q) hq[q] = hs4[(UNITS / 8) * g + q];

      // ---- Two half-dot partials, 4 independent 8-deep pk_fma chains. ----
      v2f p0a = {0.f, 0.f}, p0b = {0.f, 0.f};
      v2f p1a = {0.f, 0.f}, p1b = {0.f, 0.f};
#pragma unroll
      for (int q = 0; q < UNITS / 8; ++q) {
        v2f lo = __builtin_shufflevector(hq[q], hq[q], 0, 1);
        v2f hi = __builtin_shufflevector(hq[q], hq[q], 2, 3);
        p0a += lo * wv0[2 * q + 0];
        p0b += hi * wv0[2 * q + 1];
        p1a += lo * wv1[2 * q + 0];
        p1b += hi * wv1[2 * q + 1];
      }
      float s0 = (p0a.x + p0a.y) + (p0b.x + p0b.y);  // partial of Ky[m]
      float s1 = (p1a.x + p1a.y) + (p1b.x + p1b.y);  // partial of Ky[m+32]

      // ---- Merge halves (r1-verified): y'[lane] = K*y[lane]. ----
      v2i sw = __builtin_amdgcn_permlane32_swap(
          __float_as_int(s0), __float_as_int(s1), false, false);
      float y = __int_as_float(sw[0]) + __int_as_float(sw[1]) + a_cur;

      // r = rcp(exp(2y)+1); h = 1-2r applied implicitly via weight/P folds.
      float ex = __builtin_amdgcn_exp2f(y);
      float r = __builtin_amdgcn_rcpf(ex + 1.f);
      r_last = r;

      // Publish r for the next step (in-order DS pipe, no barrier needed).
      hsf[lane] = r;
    }
    if (c + 1 < SEQ / 64) {
      int tkb = __builtin_amdgcn_readlane(tokv[c + 1], 0);
      a = P[(long)tkb + lane];
    }
  }

  // h_T[lane] = 1 - 2*r_last;  out[row] = sigmoid(h_T . Wout + bout)
  float hT = fmaf(-2.f, r_last, 1.f);
  float psum = hT * Wout[lane];
#pragma unroll
  for (int off = 32; off > 0; off >>= 1) psum += __shfl_xor(psum, off);
  if (lane == 0) out[row] = 1.f / (1.f + __expf(-(psum + bout[0])));
}

extern "C" void kernel_launch(void* const* d_in, const int* in_sizes, int n_in,
                              void* d_out, int out_size, void* d_ws, size_t ws_size,
                              hipStream_t stream) {
  const int*   tok  = (const int*)  d_in[0];  // [BATCH, SEQ] int32
  const float* emb  = (const float*)d_in[1];  // [VOCAB, EMB]
  const float* Wxh  = (const float*)d_in[2];  // [EMB, UNITS]
  const float* Whh  = (const float*)d_in[3];  // [UNITS, UNITS]
  const float* bias = (const float*)d_in[4];  // [UNITS]
  const float* Wout = (const float*)d_in[5];  // [UNITS, 1]
  const float* bout = (const float*)d_in[6];  // [1]
  float* out = (float*)d_out;                 // [BATCH, 1] fp32

  float* P = (float*)d_ws;                    // VOCAB*UNITS fp32 = 256 KB

  proj_kernel<<<VOCAB / 4, 256, 0, stream>>>(emb, Wxh, bias, Whh, P);
  scan_kernel<<<BATCH, 64, 0, stream>>>(tok, P, Whh, Wout, bout, out);
}